// Round 13
// baseline (37.801 us; speedup 1.0000x reference)
//
#include <hip/hip_runtime.h>
#include <math.h>

typedef short bf16x8 __attribute__((ext_vector_type(8)));
typedef float f32x4 __attribute__((ext_vector_type(4)));
typedef unsigned short u16;
typedef unsigned int u32;

__device__ __forceinline__ u32 f2bf(float f) {
    u32 u = __float_as_uint(f);
    u += 0x7fffu + ((u >> 16) & 1u);
    return u >> 16;
}
__device__ __forceinline__ u32 pk2(float a, float b) {
    return f2bf(a) | (f2bf(b) << 16);
}

union U4H { uint4 u; bf16x8 h; };

// ============ fully fused: proj (per-block halo) + attention ============
// Round-11 kernel + XCD-aware bijective swizzle: bid = xcd + 8*j,
// batch b = 2*xcd + (j>>5) -> each XCD owns 2 batches; the per-block 80KB
// fp32 halo re-reads hit that XCD's L2 (256KB unique x per batch).
// 512 blocks = (b, 8x4-query tile), 4 waves. Region 20 rows x 16 cols.
// Phase 1: project region from x via MFMA (hi/lo split, fp32-accurate),
//   scatter results into LDS fragment layouts. Wave w owns m-tiles 5w..5w+4.
// Phase 2: swapped QK^T, 4-shuffle softmax, lane-local PV, MFMA epilogue.
// A/B staged with identical per-lane k maps everywhere (k-perm cancels);
// C/D (HW-verified): col=lane&15, row=(lane>>4)*4+reg.
__global__ __launch_bounds__(256, 3) void fused_kernel(
    const float* __restrict__ x,
    const float* __restrict__ Wq, const float* __restrict__ Wk,
    const float* __restrict__ Wv, const float* __restrict__ Wqxy,
    const float* __restrict__ Wkxy, const float* __restrict__ Wout,
    float* __restrict__ out)
{
    __shared__ __align__(16) u16 kfr[20 * 64 * 8];    // [t][ch>>3][sc][8ch] 20.5KB
    __shared__ __align__(16) u16 vfr[10 * 128 * 8];   // [kk][g][kd][p*4+r]  20.5KB
    __shared__ __align__(16) u16 qt[32 * 32];         // Q[q][ch]            2KB
    __shared__ __align__(16) u16 kxy4[320 * 4];       // per slot hx,hy,lx,ly 2.5KB
    __shared__ __align__(16) float qxy[32 * 2];       // per query f32 x,y   256B
    __shared__ __align__(16) u16 wfr[4 * 64 * 8];     // Wout^T frags        4KB
    __shared__ __align__(16) u16 o_l[4 * 8 * 32];     // O transpose         2KB

    int tid = threadIdx.x, bid = blockIdx.x;
    int xcd = bid & 7, j = bid >> 3;             // bijective XCD swizzle
    int b = (xcd << 1) + (j >> 5);
    int t5 = j & 31;
    int qy0 = (t5 >> 3) << 3, qx0 = (t5 & 7) << 2;
    int ry0 = qy0 - 6, rx0 = qx0 - 6;

    int w = tid >> 6, ll = tid & 63;
    int g = ll >> 4, l15 = ll & 15;

    // ---- stage Wout^T fragments (independent of phase 1)
    {
        int nt = tid >> 6, l = tid & 63;
        int cc = (nt << 4) + (l & 15);
        const float* wsrc = Wout + (cc << 5) + ((l >> 4) << 3);
        uint4 dw;
        dw.x = pk2(wsrc[0], wsrc[1]); dw.y = pk2(wsrc[2], wsrc[3]);
        dw.z = pk2(wsrc[4], wsrc[5]); dw.w = pk2(wsrc[6], wsrc[7]);
        *(uint4*)&wfr[tid << 3] = dw;
    }

    // ================= phase 1: projection of this block's region =========
    // A-frags: row (slot) = mt*16 + l15, k-elem c = ks*32 + g*8 + i
    bf16x8 ah[5][2], al[5][2];
    #pragma unroll
    for (int s = 0; s < 5; s++) {
        int mt = 5 * w + s;
        int n2 = (ry0 + mt) * 32 + rx0 + l15;
        n2 = max(0, min(1023, n2));
        #pragma unroll
        for (int ks = 0; ks < 2; ks++) {
            float av[8];
            #pragma unroll
            for (int i = 0; i < 8; i++)
                av[i] = x[(((b << 6) + (ks << 5) + (g << 3) + i) << 10) + n2];
            #pragma unroll
            for (int i = 0; i < 8; i++) {
                u32 hb = f2bf(av[i]);
                float rr = av[i] - __uint_as_float(hb << 16);
                ah[s][ks][i] = (short)hb;
                al[s][ks][i] = (short)f2bf(rr);
            }
        }
    }

    // j-tiles: 0-1 = K (Wk), 2-3 = V (Wv), 4-5 = Q (Wq), 6 = xy
    #pragma unroll
    for (int jt = 0; jt < 7; jt++) {
        f32x4 acc[5];
        #pragma unroll
        for (int s = 0; s < 5; s++) acc[s] = (f32x4){0.f, 0.f, 0.f, 0.f};

        #pragma unroll
        for (int ks = 0; ks < 2; ks++) {
            float wv[8];
            #pragma unroll
            for (int i = 0; i < 8; i++) wv[i] = 0.f;
            if (jt < 6) {
                const float* wbase = (jt < 2) ? Wk : (jt < 4) ? Wv : Wq;
                const float* wr = wbase + ((((jt & 1) << 4) + l15) << 6)
                                        + (ks << 5) + (g << 3);
                float4 wa = *(const float4*)wr, wb = *(const float4*)(wr + 4);
                wv[0] = wa.x; wv[1] = wa.y; wv[2] = wa.z; wv[3] = wa.w;
                wv[4] = wb.x; wv[5] = wb.y; wv[6] = wb.z; wv[7] = wb.w;
            } else if (l15 < 4) {
                const float* wr = ((l15 < 2) ? (Wqxy + (l15 << 6))
                                             : (Wkxy + ((l15 - 2) << 6)))
                                  + (ks << 5) + (g << 3);
                float4 wa = *(const float4*)wr, wb = *(const float4*)(wr + 4);
                wv[0] = wa.x; wv[1] = wa.y; wv[2] = wa.z; wv[3] = wa.w;
                wv[4] = wb.x; wv[5] = wb.y; wv[6] = wb.z; wv[7] = wb.w;
            }
            bf16x8 wh, wl;
            #pragma unroll
            for (int i = 0; i < 8; i++) {
                u32 hb = f2bf(wv[i]);
                float rr = wv[i] - __uint_as_float(hb << 16);
                wh[i] = (short)hb;
                wl[i] = (short)f2bf(rr);
            }
            #pragma unroll
            for (int s = 0; s < 5; s++) {
                acc[s] = __builtin_amdgcn_mfma_f32_16x16x32_bf16(ah[s][ks], wh, acc[s], 0, 0, 0);
                acc[s] = __builtin_amdgcn_mfma_f32_16x16x32_bf16(al[s][ks], wh, acc[s], 0, 0, 0);
                acc[s] = __builtin_amdgcn_mfma_f32_16x16x32_bf16(ah[s][ks], wl, acc[s], 0, 0, 0);
            }
        }

        // scatter C/D (row slot = mt*16 + g*4 + r, col j = jt*16 + l15) to LDS
        #pragma unroll
        for (int s = 0; s < 5; s++) {
            int mt = 5 * w + s;
            if (jt < 2) {                          // K: ch = jt*16 + l15
                int ch = (jt << 4) + l15;
                #pragma unroll
                for (int r = 0; r < 4; r++)
                    kfr[(((mt << 6) + ((ch >> 3) << 4) + (g << 2) + r) << 3)
                        + (ch & 7)] = (u16)f2bf(acc[s][r]);
            } else if (jt < 4) {                   // V: kd = (jt-2)*16 + l15
                int kd = ((jt - 2) << 4) + l15;
                int kk = mt >> 1, p = mt & 1;
                #pragma unroll
                for (int r = 0; r < 4; r++)
                    vfr[(kk << 10) + (g << 8) + (kd << 3) + (p << 2) + r]
                        = (u16)f2bf(acc[s][r]);
            } else if (jt < 6) {                   // Q: interior slots only
                int ch = ((jt - 4) << 4) + l15;
                if (mt >= 6 && mt <= 13) {
                    #pragma unroll
                    for (int r = 0; r < 4; r++) {
                        int sc = (g << 2) + r;
                        if (sc >= 6 && sc <= 9)
                            qt[((((mt - 6) << 2) + (sc - 6)) << 5) + ch]
                                = (u16)f2bf(acc[s][r]);
                    }
                }
            } else {                               // xy
                #pragma unroll
                for (int r = 0; r < 4; r++) {
                    float v = acc[s][r];
                    if (l15 == 2 || l15 == 3) {    // kxy: hi/lo split
                        int slot = (mt << 4) + (g << 2) + r;
                        u32 h = f2bf(v);
                        float lo = v - __uint_as_float(h << 16);
                        kxy4[(slot << 2) + (l15 - 2)]     = (u16)h;
                        kxy4[(slot << 2) + 2 + (l15 - 2)] = (u16)f2bf(lo);
                    } else if (l15 < 2) {          // qxy: interior only, f32
                        int sc = (g << 2) + r;
                        if (mt >= 6 && mt <= 13 && sc >= 6 && sc <= 9)
                            qxy[((((mt - 6) << 2) + (sc - 6)) << 1) + l15] = v;
                    }
                }
            }
        }
    }

    __syncthreads();

    // ================= phase 2: attention ==============
    int lq = ll & 15;
    int qloc = lq & 7;                         // cols 8-15 duplicate 0-7
    int qrow = (w << 1) + (qloc >> 2), qcol = qloc & 3;
    uint4 bqu = *(const uint4*)&qt[(((w << 3) + qloc) << 5) + (g << 3)];
    float2 qv = *(const float2*)&qxy[((w << 3) + qloc) << 1];
    u32 qh0 = f2bf(qv.x), qh1 = f2bf(qv.y);
    float qr0 = qv.x - __uint_as_float(qh0 << 16);
    float qr1 = qv.y - __uint_as_float(qh1 << 16);
    u32 qhp = qh0 | (qh1 << 16);
    u32 qlp = f2bf(qr0) | (f2bf(qr1) << 16);
    uint4 bxyu = make_uint4(g == 0 ? qhp : 0, g == 0 ? qlp : 0,
                            g == 0 ? qhp : 0, 0);

    // ---- QK^T (swapped) + xy-score MFMA: acc[t][r] = S[slot=t*16+4g+r][q=lq]
    f32x4 acc[20];
    #pragma unroll
    for (int t = 0; t < 20; t++) {
        uint2 kp = *(const uint2*)&kxy4[((t << 4) + lq) << 2];
        U4H axy; axy.u = make_uint4(g == 0 ? kp.x : 0, g == 0 ? kp.x : 0,
                                    g == 0 ? kp.y : 0, 0);
        U4H bxy; bxy.u = bxyu;
        f32x4 z = {0.f, 0.f, 0.f, 0.f};
        f32x4 a0 = __builtin_amdgcn_mfma_f32_16x16x32_bf16(axy.h, bxy.h, z, 0, 0, 0);
        U4H ak; ak.u = *(const uint4*)&kfr[((t << 6) + (g << 4) + lq) << 3];
        U4H bq; bq.u = bqu;
        acc[t] = __builtin_amdgcn_mfma_f32_16x16x32_bf16(ak.h, bq.h, a0, 0, 0, 0);
    }

    // ---- mask + softmax: per-lane partials + cross-g combine (4 shuffles)
    int dx2a[4], kxa[4];
    #pragma unroll
    for (int r = 0; r < 4; r++) {
        int sc = (g << 2) + r;
        int kx = rx0 + sc;
        kxa[r] = (kx >= 0) && (kx < 32);
        int dx = sc - 6 - qcol;
        dx2a[r] = dx * dx;
    }
    float m = -1e30f;
    #pragma unroll
    for (int t = 0; t < 20; t++) {
        int ky = ry0 + t;
        bool kyok = (ky >= 0) && (ky < 32);
        int dy = t - 6 - qrow, dy2 = dy * dy;
        #pragma unroll
        for (int r = 0; r < 4; r++) {
            bool ok = kyok && kxa[r] && (dy2 + dx2a[r] <= 36);
            acc[t][r] = ok ? acc[t][r] : -1e4f;
            m = fmaxf(m, acc[t][r]);
        }
    }
    m = fmaxf(m, __shfl_xor(m, 16, 64));
    m = fmaxf(m, __shfl_xor(m, 32, 64));

    float sum = 0.f;
    #pragma unroll
    for (int t = 0; t < 20; t++) {
        #pragma unroll
        for (int r = 0; r < 4; r++) {
            float e = __expf(acc[t][r] - m);
            acc[t][r] = e;
            sum += e;
        }
    }
    sum += __shfl_xor(sum, 16, 64);
    sum += __shfl_xor(sum, 32, 64);

    float rinv = 1.f / sum;
    #pragma unroll
    for (int t = 0; t < 20; t++) {
        #pragma unroll
        for (int r = 0; r < 4; r++) acc[t][r] *= rinv;   // pre-scale P (linear)
    }

    // ---- PV: k-block kk = tiles (2kk, 2kk+1) -> A-frag is lane-local acc
    f32x4 o0 = {0.f, 0.f, 0.f, 0.f}, o1 = {0.f, 0.f, 0.f, 0.f};
    #pragma unroll
    for (int kk = 0; kk < 10; kk++) {
        U4H pa;
        pa.u = make_uint4(pk2(acc[2 * kk][0],     acc[2 * kk][1]),
                          pk2(acc[2 * kk][2],     acc[2 * kk][3]),
                          pk2(acc[2 * kk + 1][0], acc[2 * kk + 1][1]),
                          pk2(acc[2 * kk + 1][2], acc[2 * kk + 1][3]));
        U4H v0; v0.u = *(const uint4*)&vfr[((kk << 7) + (g << 5) + lq) << 3];
        U4H v1; v1.u = *(const uint4*)&vfr[((kk << 7) + (g << 5) + lq + 16) << 3];
        o0 = __builtin_amdgcn_mfma_f32_16x16x32_bf16(pa.h, v0.h, o0, 0, 0, 0);
        o1 = __builtin_amdgcn_mfma_f32_16x16x32_bf16(pa.h, v1.h, o1, 0, 0, 0);
    }

    // ---- O transpose via tiny per-wave LDS (rows q<8 real; 8-15 were dups)
    if (g < 2) {
        #pragma unroll
        for (int r = 0; r < 4; r++) {
            int q = (g << 2) + r;
            o_l[(w << 8) + (q << 5) + lq]      = (u16)f2bf(o0[r]);
            o_l[(w << 8) + (q << 5) + lq + 16] = (u16)f2bf(o1[r]);
        }
    }
    __syncthreads();

    // ---- epilogue: Y = O * Wout^T, 4 column tiles
    U4H aO; aO.u = *(const uint4*)&o_l[(w << 8) + (qloc << 5) + (g << 3)];
    int nqb = (qy0 + (w << 1) + g) * 32 + qx0;   // row for q = g*4+r (g<2)
    #pragma unroll
    for (int nt2 = 0; nt2 < 4; nt2++) {
        U4H bw; bw.u = *(const uint4*)&wfr[((nt2 << 6) + ll) << 3];
        f32x4 z = {0.f, 0.f, 0.f, 0.f};
        f32x4 y = __builtin_amdgcn_mfma_f32_16x16x32_bf16(aO.h, bw.h, z, 0, 0, 0);
        if (g < 2) {
            int cc = (nt2 << 4) + lq;
            #pragma unroll
            for (int r = 0; r < 4; r++)
                out[(((b << 6) + cc) << 10) + nqb + r] = y[r];
        }
    }
}

extern "C" void kernel_launch(void* const* d_in, const int* in_sizes, int n_in,
                              void* d_out, int out_size, void* d_ws, size_t ws_size,
                              hipStream_t stream) {
    const float* x    = (const float*)d_in[0];
    const float* Wq   = (const float*)d_in[1];
    const float* Wk   = (const float*)d_in[2];
    const float* Wv   = (const float*)d_in[3];
    const float* Wqxy = (const float*)d_in[4];
    const float* Wkxy = (const float*)d_in[5];
    const float* Wout = (const float*)d_in[6];
    float* out = (float*)d_out;

    fused_kernel<<<512, 256, 0, stream>>>(x, Wq, Wk, Wv, Wqxy, Wkxy, Wout, out);
}

// Round 14
// 18.390 us; speedup vs baseline: 2.0555x; 2.0555x over previous
//
#include <hip/hip_runtime.h>
#include <math.h>

typedef short bf16x8 __attribute__((ext_vector_type(8)));
typedef float f32x4 __attribute__((ext_vector_type(4)));
typedef unsigned short u16;
typedef unsigned int u32;

// ws byte offsets: QT (B,N,32) bf16, KT (B,N,32) bf16,
// VW (B,32,1032) bf16 (1024 + 8 pad per kd row, pad zeroed by proj),
// QXY (B,N,2) f32, KXY (B,N,2) f32
#define WS_QT  0
#define WS_KT  1048576
#define WS_VW  2097152
#define WS_QXY 3153920
#define WS_KXY 3284992
#define VWS    1032

__device__ __forceinline__ u32 f2bf(float f) {
    u32 u = __float_as_uint(f);
    u += 0x7fffu + ((u >> 16) & 1u);
    return u >> 16;
}
__device__ __forceinline__ u32 pk2(float a, float b) {
    return f2bf(a) | (f2bf(b) << 16);
}

union U4H { uint4 u; bf16x8 h; };

// ---------- projections as MFMA GEMM: 1024 one-wave blocks (round-12 verbatim) ----------
__global__ __launch_bounds__(64) void proj_kernel(
    const float* __restrict__ x,
    const float* __restrict__ Wq, const float* __restrict__ Wk,
    const float* __restrict__ Wv, const float* __restrict__ Wqxy,
    const float* __restrict__ Wkxy, char* __restrict__ wsb)
{
    u16* QT = (u16*)(wsb + WS_QT);
    u16* KT = (u16*)(wsb + WS_KT);
    u16* VW = (u16*)(wsb + WS_VW);
    float* QXY = (float*)(wsb + WS_QXY);
    float* KXY = (float*)(wsb + WS_KXY);

    int l = threadIdx.x;
    int g = l >> 4, l15 = l & 15;
    int bid = blockIdx.x;
    int xcd = bid & 7, j = bid >> 3;             // bijective XCD swizzle
    int b = (xcd << 1) + (j >> 6);
    int n0 = (j & 63) << 4;

    bf16x8 ah[2], al[2];
    #pragma unroll
    for (int ks = 0; ks < 2; ks++) {
        float av[8];
        #pragma unroll
        for (int i = 0; i < 8; i++)
            av[i] = x[(((b << 6) + (ks << 5) + (g << 3) + i) << 10) + n0 + l15];
        #pragma unroll
        for (int i = 0; i < 8; i++) {
            u32 hb = f2bf(av[i]);
            float rr = av[i] - __uint_as_float(hb << 16);
            ah[ks][i] = (short)hb;
            al[ks][i] = (short)f2bf(rr);
        }
    }

    #pragma unroll
    for (int jt = 0; jt < 7; jt++) {
        f32x4 acc = {0.f, 0.f, 0.f, 0.f};
        #pragma unroll
        for (int ks = 0; ks < 2; ks++) {
            float wv[8];
            #pragma unroll
            for (int i = 0; i < 8; i++) wv[i] = 0.f;
            if (jt < 6) {
                const float* wbase = (jt < 2) ? Wq : (jt < 4) ? Wk : Wv;
                const float* wr = wbase + ((((jt & 1) << 4) + l15) << 6)
                                        + (ks << 5) + (g << 3);
                float4 wa = *(const float4*)wr, wb = *(const float4*)(wr + 4);
                wv[0] = wa.x; wv[1] = wa.y; wv[2] = wa.z; wv[3] = wa.w;
                wv[4] = wb.x; wv[5] = wb.y; wv[6] = wb.z; wv[7] = wb.w;
            } else if (l15 < 4) {
                const float* wr = ((l15 < 2) ? (Wqxy + (l15 << 6))
                                             : (Wkxy + ((l15 - 2) << 6)))
                                  + (ks << 5) + (g << 3);
                float4 wa = *(const float4*)wr, wb = *(const float4*)(wr + 4);
                wv[0] = wa.x; wv[1] = wa.y; wv[2] = wa.z; wv[3] = wa.w;
                wv[4] = wb.x; wv[5] = wb.y; wv[6] = wb.z; wv[7] = wb.w;
            }
            bf16x8 wh, wl;
            #pragma unroll
            for (int i = 0; i < 8; i++) {
                u32 hb = f2bf(wv[i]);
                float rr = wv[i] - __uint_as_float(hb << 16);
                wh[i] = (short)hb;
                wl[i] = (short)f2bf(rr);
            }
            acc = __builtin_amdgcn_mfma_f32_16x16x32_bf16(ah[ks], wh, acc, 0, 0, 0);
            acc = __builtin_amdgcn_mfma_f32_16x16x32_bf16(al[ks], wh, acc, 0, 0, 0);
            acc = __builtin_amdgcn_mfma_f32_16x16x32_bf16(ah[ks], wl, acc, 0, 0, 0);
        }
        if (jt < 2) {
            #pragma unroll
            for (int r = 0; r < 4; r++)
                QT[(((b << 10) + n0 + (g << 2) + r) << 5) + (jt << 4) + l15]
                    = (u16)f2bf(acc[r]);
        } else if (jt < 4) {
            #pragma unroll
            for (int r = 0; r < 4; r++)
                KT[(((b << 10) + n0 + (g << 2) + r) << 5) + ((jt - 2) << 4) + l15]
                    = (u16)f2bf(acc[r]);
        } else if (jt < 6) {
            int kd = ((jt - 4) << 4) + l15;
            uint2 d = make_uint2(pk2(acc[0], acc[1]), pk2(acc[2], acc[3]));
            *(uint2*)&VW[((b << 5) + kd) * VWS + n0 + (g << 2)] = d;
        } else {
            if (l15 < 2) {
                #pragma unroll
                for (int r = 0; r < 4; r++)
                    QXY[(((b << 10) + n0 + (g << 2) + r) << 1) + l15] = acc[r];
            } else if (l15 < 4) {
                #pragma unroll
                for (int r = 0; r < 4; r++)
                    KXY[(((b << 10) + n0 + (g << 2) + r) << 1) + (l15 - 2)] = acc[r];
            }
        }
    }

    if ((j & 63) == 63 && l < 32)
        *(uint4*)&VW[((b << 5) + l) * VWS + 1024] = make_uint4(0, 0, 0, 0);
}

// ---------- attention: 256 blocks = (b, 16x4-query tile); wave = 16 queries ----
// Region 28 rows x 16 cols. Wave w owns query rows 4w..4w+3 (16 distinct
// queries = all 16 MFMA B-cols used) and region rows 4w..4w+15 (exactly the
// reachable keys). Swapped QK^T, 4-shuffle softmax, lane-local PV (k-block =
// even row-pair m=2w+kk, identical A/B k-perm), MFMA epilogue on all lanes.
// LDS 65KB; O-transpose aliases kfr (dead after QK) behind a barrier.
__global__ __launch_bounds__(256, 1) void attn_kernel(
    const char* __restrict__ wsb, const float* __restrict__ Wout,
    float* __restrict__ out)
{
    const u16* QT = (const u16*)(wsb + WS_QT);
    const u16* KT = (const u16*)(wsb + WS_KT);
    const u16* VW = (const u16*)(wsb + WS_VW);
    const float* QXY = (const float*)(wsb + WS_QXY);
    const float* KXY = (const float*)(wsb + WS_KXY);

    // flat LDS: kfr 0..14335 (28 row-tiles), vfr 14336..28671 (14 pairs),
    // kxy 28672..30463 (448 slots x 4 u16), wfr 30464..32511. 65024 B.
    __shared__ __align__(16) u16 smem[32512];
    u16* kfr = smem;
    u16* vfr = smem + 14336;
    u32* kxyb = (u32*)(smem + 28672);
    u16* wfr = smem + 30464;
    u16* o_l = smem;                 // aliases kfr after QK (barrier-protected)

    int tid = threadIdx.x, bid = blockIdx.x;
    int xcd = bid & 7, j = bid >> 3;             // bijective XCD swizzle
    int b = (xcd << 1) + (j >> 4);
    int t4 = j & 15;
    int qy0 = (t4 >> 3) << 4, qx0 = (t4 & 7) << 2;
    int ry0 = qy0 - 6, rx0 = qx0 - 6;

    // ---- stage K fragments: 1792 chunks, c -> (t=c>>6, g2=(c>>4)&3, sc=c&15)
    #pragma unroll
    for (int i = 0; i < 7; i++) {
        int c = tid + (i << 8);
        int t = c >> 6, g2 = (c >> 4) & 3, sc = c & 15;
        int n2 = (ry0 + t) * 32 + rx0 + sc;
        n2 = max(0, min(1023, n2));
        uint4 d = *(const uint4*)(KT + (((b << 10) + n2) << 5) + (g2 << 3));
        *(uint4*)&kfr[c << 3] = d;
    }
    // ---- stage V fragments: 3584 granules, d -> (p,kd,g2,pair m=d>>8)
    #pragma unroll
    for (int i = 0; i < 14; i++) {
        int d = tid + (i << 8);
        int p = d & 1, kd = (d >> 1) & 31, g2 = (d >> 6) & 3, m = d >> 8;
        int ky = ry0 + (m << 1) + p;
        int n = ky * 32 + rx0 + (g2 << 2);
        if ((u32)ky > 31u) n = 0;               // masked rows -> finite data
        const u32* s = (const u32*)(VW + ((b << 5) + kd) * VWS + n);
        *(uint2*)&vfr[d << 2] = make_uint2(s[0], s[1]);
    }
    // ---- stage kxy hi/lo packed per slot (448 slots)
    for (int i = tid; i < 448; i += 256) {
        int n2 = (ry0 + (i >> 4)) * 32 + rx0 + (i & 15);
        n2 = max(0, min(1023, n2));
        float2 f = *(const float2*)(KXY + (((b << 10) + n2) << 1));
        u32 h0 = f2bf(f.x), h1 = f2bf(f.y);
        float r0 = f.x - __uint_as_float(h0 << 16);
        float r1 = f.y - __uint_as_float(h1 << 16);
        kxyb[(i << 1)]     = h0 | (h1 << 16);
        kxyb[(i << 1) + 1] = f2bf(r0) | (f2bf(r1) << 16);
    }
    // ---- stage Wout^T fragments
    {
        int nt = tid >> 6, l = tid & 63;
        int cc = (nt << 4) + (l & 15);
        const float* wsrc = Wout + (cc << 5) + ((l >> 4) << 3);
        uint4 dw;
        dw.x = pk2(wsrc[0], wsrc[1]); dw.y = pk2(wsrc[2], wsrc[3]);
        dw.z = pk2(wsrc[4], wsrc[5]); dw.w = pk2(wsrc[6], wsrc[7]);
        *(uint4*)&wfr[tid << 3] = dw;
    }

    // ---- per-lane query setup (global reads, issued pre-barrier)
    int w = tid >> 6, ll = tid & 63;
    int lq = ll & 15, g = ll >> 4;
    int qrl = lq >> 2, qcol = lq & 3;           // query row/col within wave
    int nq = (qy0 + (w << 2) + qrl) * 32 + qx0 + qcol;
    uint4 bqu = *(const uint4*)(QT + (((b << 10) + nq) << 5) + (g << 3));
    float2 qv = *(const float2*)(QXY + (((b << 10) + nq) << 1));
    u32 qh0 = f2bf(qv.x), qh1 = f2bf(qv.y);
    float qr0 = qv.x - __uint_as_float(qh0 << 16);
    float qr1 = qv.y - __uint_as_float(qh1 << 16);
    u32 qhp = qh0 | (qh1 << 16);
    u32 qlp = f2bf(qr0) | (f2bf(qr1) << 16);
    uint4 bxyu = make_uint4(g == 0 ? qhp : 0, g == 0 ? qlp : 0,
                            g == 0 ? qhp : 0, 0);

    __syncthreads();

    // ---- QK^T (swapped) + xy MFMA over the wave's 16 region rows
    // acc[t][r] = S[slot=(4w+t)*16 + 4g+r][q=lq]
    f32x4 acc[16];
    #pragma unroll
    for (int t = 0; t < 16; t++) {
        int rr = (w << 2) + t;
        uint2 kp = *(const uint2*)&kxyb[((rr << 4) + lq) << 1];
        U4H axy; axy.u = make_uint4(g == 0 ? kp.x : 0, g == 0 ? kp.x : 0,
                                    g == 0 ? kp.y : 0, 0);
        U4H bxy; bxy.u = bxyu;
        f32x4 z = {0.f, 0.f, 0.f, 0.f};
        f32x4 a0 = __builtin_amdgcn_mfma_f32_16x16x32_bf16(axy.h, bxy.h, z, 0, 0, 0);
        U4H ak; ak.u = *(const uint4*)&kfr[((rr << 6) + (g << 4) + lq) << 3];
        U4H bq; bq.u = bqu;
        acc[t] = __builtin_amdgcn_mfma_f32_16x16x32_bf16(ak.h, bq.h, a0, 0, 0, 0);
    }

    // ---- mask + softmax: per-lane partials + cross-g combine (4 shuffles)
    int dx2a[4], kxa[4];
    #pragma unroll
    for (int r = 0; r < 4; r++) {
        int sc = (g << 2) + r;
        int kx = rx0 + sc;
        kxa[r] = (kx >= 0) && (kx < 32);
        int dx = sc - 6 - qcol;
        dx2a[r] = dx * dx;
    }
    float m = -1e30f;
    #pragma unroll
    for (int t = 0; t < 16; t++) {
        int ky = ry0 + (w << 2) + t;
        bool kyok = (ky >= 0) && (ky < 32);
        int dy = t - 6 - qrl, dy2 = dy * dy;
        #pragma unroll
        for (int r = 0; r < 4; r++) {
            bool ok = kyok && kxa[r] && (dy2 + dx2a[r] <= 36);
            acc[t][r] = ok ? acc[t][r] : -1e4f;
            m = fmaxf(m, acc[t][r]);
        }
    }
    m = fmaxf(m, __shfl_xor(m, 16, 64));
    m = fmaxf(m, __shfl_xor(m, 32, 64));

    float sum = 0.f;
    #pragma unroll
    for (int t = 0; t < 16; t++) {
        #pragma unroll
        for (int r = 0; r < 4; r++) {
            float e = __expf(acc[t][r] - m);
            acc[t][r] = e;
            sum += e;
        }
    }
    sum += __shfl_xor(sum, 16, 64);
    sum += __shfl_xor(sum, 32, 64);

    float rinv = 1.f / sum;
    #pragma unroll
    for (int t = 0; t < 16; t++) {
        #pragma unroll
        for (int r = 0; r < 4; r++) acc[t][r] *= rinv;   // pre-scale P (linear)
    }

    // ---- PV: k-block kk = even row pair m2 = 2w+kk -> A-frag lane-local
    f32x4 o0 = {0.f, 0.f, 0.f, 0.f}, o1 = {0.f, 0.f, 0.f, 0.f};
    #pragma unroll
    for (int kk = 0; kk < 8; kk++) {
        int m2 = (w << 1) + kk;
        U4H pa;
        pa.u = make_uint4(pk2(acc[2 * kk][0],     acc[2 * kk][1]),
                          pk2(acc[2 * kk][2],     acc[2 * kk][3]),
                          pk2(acc[2 * kk + 1][0], acc[2 * kk + 1][1]),
                          pk2(acc[2 * kk + 1][2], acc[2 * kk + 1][3]));
        U4H v0; v0.u = *(const uint4*)&vfr[((m2 << 7) + (g << 5) + lq) << 3];
        U4H v1; v1.u = *(const uint4*)&vfr[((m2 << 7) + (g << 5) + lq + 16) << 3];
        o0 = __builtin_amdgcn_mfma_f32_16x16x32_bf16(pa.h, v0.h, o0, 0, 0, 0);
        o1 = __builtin_amdgcn_mfma_f32_16x16x32_bf16(pa.h, v1.h, o1, 0, 0, 0);
    }

    // ---- O transpose via LDS (aliases kfr -> barrier first)
    __syncthreads();
    #pragma unroll
    for (int r = 0; r < 4; r++) {
        int q = (g << 2) + r;
        o_l[(w << 9) + (q << 5) + lq]      = (u16)f2bf(o0[r]);
        o_l[(w << 9) + (q << 5) + lq + 16] = (u16)f2bf(o1[r]);
    }
    __syncthreads();

    // ---- epilogue: Y = O * Wout^T, 4 column tiles, all 64 lanes active
    U4H aO; aO.u = *(const uint4*)&o_l[(w << 9) + (lq << 5) + (g << 3)];
    int nqb = (qy0 + (w << 2) + g) * 32 + qx0;   // row for q = 4g+r
    #pragma unroll
    for (int nt2 = 0; nt2 < 4; nt2++) {
        U4H bw; bw.u = *(const uint4*)&wfr[((nt2 << 6) + ll) << 3];
        f32x4 z = {0.f, 0.f, 0.f, 0.f};
        f32x4 y = __builtin_amdgcn_mfma_f32_16x16x32_bf16(aO.h, bw.h, z, 0, 0, 0);
        int cc = (nt2 << 4) + lq;
        #pragma unroll
        for (int r = 0; r < 4; r++)
            out[(((b << 6) + cc) << 10) + nqb + r] = y[r];
    }
}

extern "C" void kernel_launch(void* const* d_in, const int* in_sizes, int n_in,
                              void* d_out, int out_size, void* d_ws, size_t ws_size,
                              hipStream_t stream) {
    const float* x    = (const float*)d_in[0];
    const float* Wq   = (const float*)d_in[1];
    const float* Wk   = (const float*)d_in[2];
    const float* Wv   = (const float*)d_in[3];
    const float* Wqxy = (const float*)d_in[4];
    const float* Wkxy = (const float*)d_in[5];
    const float* Wout = (const float*)d_in[6];
    float* out = (float*)d_out;
    char* wsb  = (char*)d_ws;

    proj_kernel<<<1024, 64, 0, stream>>>(x, Wq, Wk, Wv, Wqxy, Wkxy, wsb);
    attn_kernel<<<256, 256, 0, stream>>>(wsb, Wout, out);
}